// Round 16
// baseline (76.127 us; speedup 1.0000x reference)
//
#include <hip/hip_runtime.h>

#define N_NODES 16384
#define NE 524288
#define KDIM 1152          // IN*NG + IN (permuted into 2 phases of 576)
#define KPH 576            // K per phase
#define KPAD2 584          // padded LDS row (ushorts), 16B-aligned stride
#define KSTEPS_PH 18       // 576 / 32
#define NBUCK 1024         // buckets of 16 nodes
#define SBLK 512           // sort blocks; each owns 1024 edges = 2048 entries
#define SPB 2048           // directed entries per sort block (exact)
#define MROW 516           // padded LDS row stride (words) for degb bitmask
#define DCAP 256           // per-node dedup'd neighbor capacity (mean 64)

typedef unsigned int uint32;
typedef unsigned short ushort;
typedef __attribute__((ext_vector_type(8))) short bf16x8;
typedef __attribute__((ext_vector_type(4))) float f32x4;

__device__ __forceinline__ ushort f2bf(float f) {
    unsigned u = __float_as_uint(f);
    unsigned r = (u + 0x7fffu + ((u >> 16) & 1u)) >> 16;
    return (ushort)r;
}
__device__ __forceinline__ float bflo(uint32 u) {
    return __uint_as_float(u << 16);
}
__device__ __forceinline__ float bfhi(uint32 u) {
    return __uint_as_float(u & 0xffff0000u);
}

// ===== launch 1: in-LDS bucket sort (blocks 0..511) + weight pack (512..1087) =====
__global__ __launch_bounds__(256) void pre_kernel(
    const int* __restrict__ ei, uint32* __restrict__ ebuf,
    uint32* __restrict__ ocnt, const float* __restrict__ sw,
    const float* __restrict__ bw, ushort* __restrict__ Wp) {
    const int t = threadIdx.x;
    if (blockIdx.x >= SBLK) {
        int idx = (blockIdx.x - SBLK) * 256 + t;   // 0 .. 147455
        int i  = idx & 7;
        int l  = (idx >> 3) & 63;
        int ct = (idx >> 9) & 7;
        int kk = idx >> 12;                         // 0..35
        int kp  = kk * 32 + ((l >> 4) << 3) + i;    // permuted k'
        int p   = kp / KPH;
        int r   = kp - p * KPH;
        int col = ct * 16 + (l & 15);
        float v;
        if (r < 512) {
            int ch = p * 64 + (r >> 3);
            int g  = r & 7;
            v = sw[col * 1024 + ch * 8 + g];
        } else {
            int ch = p * 64 + (r - 512);
            v = bw[col * 128 + ch];
        }
        Wp[idx] = f2bf(v);
        return;
    }
    __shared__ int hcnt[NBUCK];                    // 4 KB
    __shared__ int lbase[NBUCK];                   // 4 KB
    __shared__ int ps[256];                        // 1 KB
    __shared__ uint32 st[SPB];                     // 8 KB
    for (int q = t; q < NBUCK; q += 256) hcnt[q] = 0;
    __syncthreads();

    int bk[8], sl[8];
    uint32 pk[8];
#pragma unroll
    for (int k = 0; k < 4; ++k) {
        int e = blockIdx.x * 1024 + k * 256 + t;
        int a = ei[e];
        int b = ei[NE + e];
        bk[2 * k]     = a >> 4;
        pk[2 * k]     = ((uint32)(a & 15) << 14) | (uint32)b;
        bk[2 * k + 1] = b >> 4;
        pk[2 * k + 1] = ((uint32)(b & 15) << 14) | (uint32)a;
        sl[2 * k]     = atomicAdd(&hcnt[bk[2 * k]], 1);
        sl[2 * k + 1] = atomicAdd(&hcnt[bk[2 * k + 1]], 1);
    }
    __syncthreads();

    int c[4], loc[4];
    int s = 0;
#pragma unroll
    for (int q = 0; q < 4; ++q) {
        c[q] = hcnt[t * 4 + q];
        loc[q] = s;
        s += c[q];
    }
    ps[t] = s;
    __syncthreads();
    for (int off = 1; off < 256; off <<= 1) {
        int v = ps[t];
        int add = (t >= off) ? ps[t - off] : 0;
        __syncthreads();
        ps[t] = v + add;
        __syncthreads();
    }
    const int base = (t == 0) ? 0 : ps[t - 1];
    uint32* oc = ocnt + (size_t)blockIdx.x * NBUCK;
#pragma unroll
    for (int q = 0; q < 4; ++q) {
        int e0 = base + loc[q];
        lbase[t * 4 + q] = e0;
        oc[t * 4 + q] = (uint32)e0 | ((uint32)c[q] << 16);
    }
    __syncthreads();

#pragma unroll
    for (int k = 0; k < 8; ++k) st[lbase[bk[k]] + sl[k]] = pk[k];
    __syncthreads();
    uint32* gout = ebuf + (size_t)blockIdx.x * SPB;
#pragma unroll
    for (int k = 0; k < 8; ++k) gout[t + k * 256] = st[t + k * 256];
}

// ===== launch 2: mod-3 interleave — degb (roles 0,1) + 32-node support (role 2) =====
// degb emits dadj PARTITIONED: entries with nbr<8192 first, then >=8192;
// degarr[node] = deg | (cntLow << 16).
__global__ __launch_bounds__(256) void mid_kernel(
    const uint32* __restrict__ ebuf, const uint32* __restrict__ ocnt,
    float* __restrict__ dis, int* __restrict__ degarr,
    ushort* __restrict__ dadj, const float* __restrict__ x,
    const float* __restrict__ gamma, const float* __restrict__ beta,
    const ushort* __restrict__ Wp, const float* __restrict__ base_b,
    ushort* __restrict__ S) {
    __shared__ __align__(16) ushort smem[32 * KPAD2];       // 37,376 B
    const int t = threadIdx.x;
    const int lane = t & 63;
    const int w = t >> 6;
    const int role = blockIdx.x % 3;

    if (role < 2) {
        uint32* mask = (uint32*)smem;
        const int bkt = (blockIdx.x / 3) * 2 + role;
        for (int i = t; i < 16 * MROW; i += 256) mask[i] = 0;
        __syncthreads();

        const uint32 oc0 = ocnt[(size_t)t * NBUCK + bkt];
        const uint32 oc1 = ocnt[(size_t)(t + 256) * NBUCK + bkt];
#pragma unroll
        for (int h = 0; h < 2; ++h) {
            const int b = h ? (t + 256) : t;
            const uint32 oc = h ? oc1 : oc0;
            int off = (int)(oc & 0xFFFFu);
            int cn  = (int)(oc >> 16);
            const uint32* p = ebuf + (size_t)b * SPB + off;
            for (int s = 0; s < cn; ++s) {
                uint32 e = p[s];
                atomicOr(&mask[(e >> 14) * MROW + ((e & 16383) >> 5)],
                         1u << (e & 31));
            }
        }
        __syncthreads();

        for (int n = w * 4; n < w * 4 + 4; ++n) {
            const uint32* row = &mask[n * MROW];
            uint32 wd[8];
            int cL = 0, cH = 0;
#pragma unroll
            for (int j = 0; j < 4; ++j) {
                wd[j] = row[lane + 64 * j];
                cL += __popc(wd[j]);
            }
#pragma unroll
            for (int j = 4; j < 8; ++j) {
                wd[j] = row[lane + 64 * j];
                cH += __popc(wd[j]);
            }
            int incL = cL;
#pragma unroll
            for (int o = 1; o < 64; o <<= 1) {
                int v = __shfl_up(incL, o);
                if (lane >= o) incL += v;
            }
            const int totalL = __shfl(incL, 63);
            int incH = cH;
#pragma unroll
            for (int o = 1; o < 64; o <<= 1) {
                int v = __shfl_up(incH, o);
                if (lane >= o) incH += v;
            }
            const int totalH = __shfl(incH, 63);
            const int total = totalL + totalH;
            const int node = bkt * 16 + n;
            if (lane == 0) {
                dis[node] = rsqrtf((float)total);
                int dcl = total > DCAP ? DCAP : total;
                int lcl = totalL > DCAP ? DCAP : totalL;
                degarr[node] = dcl | (lcl << 16);
            }
            ushort* drow = dadj + (size_t)node * DCAP;
            int pos = incL - cL;                    // low-half exclusive base
#pragma unroll
            for (int j = 0; j < 4; ++j) {
                uint32 bits = wd[j];
                int base = (lane + 64 * j) * 32;
                while (bits) {
                    int b = __ffs(bits) - 1;
                    bits &= bits - 1;
                    if (pos < DCAP) drow[pos] = (ushort)(base + b);
                    ++pos;
                }
            }
            pos = totalL + incH - cH;               // high-half base
#pragma unroll
            for (int j = 4; j < 8; ++j) {
                uint32 bits = wd[j];
                int base = (lane + 64 * j) * 32;
                while (bits) {
                    int b = __ffs(bits) - 1;
                    bits &= bits - 1;
                    if (pos < DCAP) drow[pos] = (ushort)(base + b);
                    ++pos;
                }
            }
        }
        return;
    }

    // ---- support: 32 nodes/block, two K-phases sharing Bs[32][KPAD2] ----
    ushort* Bs = smem;
    const int nodeBase = (blockIdx.x / 3) * 32;

    const float g0 = gamma[lane], g1 = gamma[lane + 64];
    const float be0 = beta[lane], be1 = beta[lane + 64];

    float h0r[8], h1r[8], f0r[8], f1r[8];
#pragma unroll
    for (int j = 0; j < 8; ++j) {
        const int row = nodeBase + w * 8 + j;
        float f0 = x[(size_t)row * 128 + lane];
        float f1 = x[(size_t)row * 128 + lane + 64];
        float s = f0 + f1;
#pragma unroll
        for (int o = 32; o; o >>= 1) s += __shfl_xor(s, o);
        float mu = s * 0.0078125f;
        float d0 = f0 - mu, d1 = f1 - mu;
        float v = d0 * d0 + d1 * d1;
#pragma unroll
        for (int o = 32; o; o >>= 1) v += __shfl_xor(v, o);
        float rstd = rsqrtf(v * 0.0078125f + 1e-5f);
        h0r[j] = d0 * rstd * g0 + be0;
        h1r[j] = d1 * rstd * g1 + be1;
        f0r[j] = f0;
        f1r[j] = f1;
    }

    const int ct0 = w * 2;
    f32x4 accA = {0.f, 0.f, 0.f, 0.f};
    f32x4 accB = {0.f, 0.f, 0.f, 0.f};
    f32x4 accC = {0.f, 0.f, 0.f, 0.f};
    f32x4 accD = {0.f, 0.f, 0.f, 0.f};
    const ushort* Alo = &Bs[(lane & 15) * KPAD2 + (lane >> 4) * 8];
    const ushort* Ahi = Alo + 16 * KPAD2;
    const bf16x8* Wv = (const bf16x8*)Wp;

#pragma unroll
    for (int p = 0; p < 2; ++p) {
        if (p) __syncthreads();
#pragma unroll
        for (int j = 0; j < 8; ++j) {
            const int n = w * 8 + j;
            const float h = p ? h1r[j] : h0r[j];
            const float f = p ? f1r[j] : f0r[j];
            ushort pk[8] __attribute__((aligned(16)));
#pragma unroll
            for (int g = 0; g < 8; ++g) {
                float gv = -2.0f + (float)g * (4.0f / 7.0f);
                float z = (h - gv) * 1.75f;
                pk[g] = f2bf(__expf(-z * z));
            }
            *reinterpret_cast<uint4*>(&Bs[n * KPAD2 + lane * 8]) =
                *reinterpret_cast<const uint4*>(pk);
            Bs[n * KPAD2 + 512 + lane] = f2bf(f / (1.0f + __expf(-f)));
        }
        __syncthreads();

#pragma unroll 3
        for (int kkl = 0; kkl < KSTEPS_PH; ++kkl) {
            const int kkg = p * KSTEPS_PH + kkl;
            bf16x8 alo = *reinterpret_cast<const bf16x8*>(Alo + kkl * 32);
            bf16x8 ahi = *reinterpret_cast<const bf16x8*>(Ahi + kkl * 32);
            bf16x8 b0 = Wv[(size_t)(kkg * 8 + ct0) * 64 + lane];
            bf16x8 b1 = Wv[(size_t)(kkg * 8 + ct0 + 1) * 64 + lane];
            accA = __builtin_amdgcn_mfma_f32_16x16x32_bf16(alo, b0, accA, 0, 0, 0);
            accB = __builtin_amdgcn_mfma_f32_16x16x32_bf16(alo, b1, accB, 0, 0, 0);
            accC = __builtin_amdgcn_mfma_f32_16x16x32_bf16(ahi, b0, accC, 0, 0, 0);
            accD = __builtin_amdgcn_mfma_f32_16x16x32_bf16(ahi, b1, accD, 0, 0, 0);
        }
    }

    const int col0 = ct0 * 16 + (lane & 15);
    const int rbase = (lane >> 4) * 4;
    const float bb0 = base_b[col0];
    const float bb1 = base_b[col0 + 16];
#pragma unroll
    for (int r = 0; r < 4; ++r) {
        const int rlo = nodeBase + rbase + r;
        const int rhi = rlo + 16;
        S[(size_t)rlo * 128 + col0]      = f2bf(accA[r] + bb0);
        S[(size_t)rlo * 128 + col0 + 16] = f2bf(accB[r] + bb1);
        S[(size_t)rhi * 128 + col0]      = f2bf(accC[r] + bb0);
        S[(size_t)rhi * 128 + col0 + 16] = f2bf(accD[r] + bb1);
    }
}

// ===== launches 3&4: range-phased aggregation (S working set 2 MB per pass) =====
// pass 0: neighbors < 8192 -> out = raw f32 partial
// pass 1: neighbors >= 8192 -> out = (out + partial) * dis_i + bias
__global__ __launch_bounds__(256) void aggregate_kernel(
    const int pass, const int* __restrict__ degarr,
    const ushort* __restrict__ dadj, const ushort* __restrict__ S,
    const float* __restrict__ dis, const float* __restrict__ bias,
    float* __restrict__ out) {
    __shared__ ushort lst[2][DCAP];
    __shared__ float part[2][2][128];
    const int t = threadIdx.x;
    const int g = t >> 7;
    const int tl = t & 127;
    const int i = blockIdx.x * 2 + g;

    const int dp = degarr[i];
    const int deg = dp & 0xFFFF;
    const int cLow = dp >> 16;
    const int lo = pass ? cLow : 0;
    const int total = pass ? (deg - cLow) : cLow;
    const ushort* drow = dadj + (size_t)i * DCAP + lo;
    if (tl < total) lst[g][tl] = drow[tl];
    if (tl + 128 < total) lst[g][tl + 128] = drow[tl + 128];
    __syncthreads();

    const int lane = t & 63;
    const int wv = (t >> 6) & 1;
    const int slot = lane >> 4;                      // row slot 0..3 in quad
    const int cl = lane & 15;                        // 16B chunk within row
    const uint4* S128 = (const uint4*)S;             // row stride 16 uint4
    float acc[8] = {0.f, 0.f, 0.f, 0.f, 0.f, 0.f, 0.f, 0.f};

    for (int base = wv * 4; base < total; base += 16) {
        const int ia = base + slot;
        const int ib = base + 8 + slot;
        const int ja = lst[g][ia < total ? ia : (total - 1)];
        const int jb = lst[g][ib < total ? ib : (total - 1)];
        const float da = (ia < total) ? dis[ja] : 0.0f;
        const float db = (ib < total) ? dis[jb] : 0.0f;
        const uint4 ua = S128[(size_t)ja * 16 + cl];
        const uint4 ub = S128[(size_t)jb * 16 + cl];
        acc[0] += da * bflo(ua.x) + db * bflo(ub.x);
        acc[1] += da * bfhi(ua.x) + db * bfhi(ub.x);
        acc[2] += da * bflo(ua.y) + db * bflo(ub.y);
        acc[3] += da * bfhi(ua.y) + db * bfhi(ub.y);
        acc[4] += da * bflo(ua.z) + db * bflo(ub.z);
        acc[5] += da * bfhi(ua.z) + db * bfhi(ub.z);
        acc[6] += da * bflo(ua.w) + db * bflo(ub.w);
        acc[7] += da * bfhi(ua.w) + db * bfhi(ub.w);
    }

#pragma unroll
    for (int e = 0; e < 8; ++e) {
        acc[e] += __shfl_xor(acc[e], 16);
        acc[e] += __shfl_xor(acc[e], 32);
    }
    if (lane < 16) {
        float4 v0 = {acc[0], acc[1], acc[2], acc[3]};
        float4 v1 = {acc[4], acc[5], acc[6], acc[7]};
        *reinterpret_cast<float4*>(&part[g][wv][cl * 8])     = v0;
        *reinterpret_cast<float4*>(&part[g][wv][cl * 8 + 4]) = v1;
    }
    __syncthreads();

    float v = part[g][0][tl] + part[g][1][tl];
    if (pass == 0)
        out[(size_t)i * 128 + tl] = v;
    else
        out[(size_t)i * 128 + tl] =
            (out[(size_t)i * 128 + tl] + v) * dis[i] + bias[tl];
}

extern "C" void kernel_launch(void* const* d_in, const int* in_sizes, int n_in,
                              void* d_out, int out_size, void* d_ws, size_t ws_size,
                              hipStream_t stream) {
    const float* x        = (const float*)d_in[0];
    const int*   ei       = (const int*)d_in[1];
    const float* ln_gamma = (const float*)d_in[2];
    const float* ln_beta  = (const float*)d_in[3];
    const float* spline_w = (const float*)d_in[4];
    const float* base_w   = (const float*)d_in[5];
    const float* base_b   = (const float*)d_in[6];
    const float* bias     = (const float*)d_in[7];
    float* out = (float*)d_out;

    char* ws = (char*)d_ws;
    const size_t WP_OFF   = 0;             //    294,912 B
    const size_t DIS_OFF  = 294912;        //     65,536 B
    const size_t DEG_OFF  = 360448;        //     65,536 B
    const size_t DADJ_OFF = 425984;        //  8,388,608 B
    const size_t OCNT_OFF = 8814592;       //  2,097,152 B (512 x 1024 u32)
    const size_t EBUF_OFF = 10911744;      //  4,194,304 B
    const size_t S_OFF    = 15106048;      //  4,194,304 B
    const size_t NEEDED   = 19300352;
    if (ws_size < NEEDED) return;

    ushort* Wp     = (ushort*)(ws + WP_OFF);
    float*  dis    = (float*)(ws + DIS_OFF);
    int*    degarr = (int*)(ws + DEG_OFF);
    ushort* dadj   = (ushort*)(ws + DADJ_OFF);
    uint32* ocnt   = (uint32*)(ws + OCNT_OFF);
    uint32* ebuf   = (uint32*)(ws + EBUF_OFF);
    ushort* S      = (ushort*)(ws + S_OFF);

    pre_kernel<<<SBLK + 576, 256, 0, stream>>>(ei, ebuf, ocnt,
                                               spline_w, base_w, Wp);
    mid_kernel<<<1536, 256, 0, stream>>>(ebuf, ocnt, dis, degarr, dadj,
                                         x, ln_gamma, ln_beta, Wp, base_b, S);
    aggregate_kernel<<<N_NODES / 2, 256, 0, stream>>>(0, degarr, dadj, S, dis,
                                                      bias, out);
    aggregate_kernel<<<N_NODES / 2, 256, 0, stream>>>(1, degarr, dadj, S, dis,
                                                      bias, out);
}

// Round 17
// 65.932 us; speedup vs baseline: 1.1546x; 1.1546x over previous
//
#include <hip/hip_runtime.h>

#define N_NODES 16384
#define NE 524288
#define KDIM 1152          // IN*NG + IN (permuted into 2 phases of 576)
#define KPH 576            // K per phase
#define KPAD2 584          // padded LDS row (ushorts), 16B-aligned stride
#define KSTEPS_PH 18       // 576 / 32
#define NBUCK 1024         // buckets of 16 nodes
#define SBLK 512           // sort blocks; each owns 1024 edges = 2048 entries
#define SPB 2048           // directed entries per sort block (exact)
#define MROW 516           // padded LDS row stride (words) for degb bitmask
#define DCAP 256           // per-node dedup'd neighbor capacity (mean 64)

typedef unsigned int uint32;
typedef unsigned short ushort;
typedef __attribute__((ext_vector_type(8))) short bf16x8;
typedef __attribute__((ext_vector_type(4))) float f32x4;

__device__ __forceinline__ ushort f2bf(float f) {
    unsigned u = __float_as_uint(f);
    unsigned r = (u + 0x7fffu + ((u >> 16) & 1u)) >> 16;
    return (ushort)r;
}
__device__ __forceinline__ float bflo(uint32 u) {
    return __uint_as_float(u << 16);
}
__device__ __forceinline__ float bfhi(uint32 u) {
    return __uint_as_float(u & 0xffff0000u);
}

// ===== launch 1: in-LDS bucket sort (blocks 0..511) + weight pack (512..1087) =====
// Wp uses PERMUTED K order: phase p in {0,1} covers k' in [p*576,(p+1)*576):
//   r = k' % 576; r<512: ch = p*64 + (r>>3), g = r&7  (RBF of channel ch)
//                 r>=512: ch = p*64 + (r-512)          (silu of channel ch)
__global__ __launch_bounds__(256) void pre_kernel(
    const int* __restrict__ ei, uint32* __restrict__ ebuf,
    uint32* __restrict__ ocnt, const float* __restrict__ sw,
    const float* __restrict__ bw, ushort* __restrict__ Wp) {
    const int t = threadIdx.x;
    if (blockIdx.x >= SBLK) {
        int idx = (blockIdx.x - SBLK) * 256 + t;   // 0 .. 147455
        int i  = idx & 7;
        int l  = (idx >> 3) & 63;
        int ct = (idx >> 9) & 7;
        int kk = idx >> 12;                         // 0..35
        int kp  = kk * 32 + ((l >> 4) << 3) + i;    // permuted k'
        int p   = kp / KPH;
        int r   = kp - p * KPH;
        int col = ct * 16 + (l & 15);
        float v;
        if (r < 512) {
            int ch = p * 64 + (r >> 3);
            int g  = r & 7;
            v = sw[col * 1024 + ch * 8 + g];
        } else {
            int ch = p * 64 + (r - 512);
            v = bw[col * 128 + ch];
        }
        Wp[idx] = f2bf(v);
        return;
    }
    __shared__ int hcnt[NBUCK];                    // 4 KB
    __shared__ int lbase[NBUCK];                   // 4 KB
    __shared__ int ps[256];                        // 1 KB
    __shared__ uint32 st[SPB];                     // 8 KB
    for (int q = t; q < NBUCK; q += 256) hcnt[q] = 0;
    __syncthreads();

    int bk[8], sl[8];
    uint32 pk[8];
#pragma unroll
    for (int k = 0; k < 4; ++k) {
        int e = blockIdx.x * 1024 + k * 256 + t;
        int a = ei[e];
        int b = ei[NE + e];
        bk[2 * k]     = a >> 4;
        pk[2 * k]     = ((uint32)(a & 15) << 14) | (uint32)b;
        bk[2 * k + 1] = b >> 4;
        pk[2 * k + 1] = ((uint32)(b & 15) << 14) | (uint32)a;
        sl[2 * k]     = atomicAdd(&hcnt[bk[2 * k]], 1);
        sl[2 * k + 1] = atomicAdd(&hcnt[bk[2 * k + 1]], 1);
    }
    __syncthreads();

    // exclusive scan over 1024 counts: 4-chunk local + Hillis-Steele over 256
    int c[4], loc[4];
    int s = 0;
#pragma unroll
    for (int q = 0; q < 4; ++q) {
        c[q] = hcnt[t * 4 + q];
        loc[q] = s;
        s += c[q];
    }
    ps[t] = s;
    __syncthreads();
    for (int off = 1; off < 256; off <<= 1) {
        int v = ps[t];
        int add = (t >= off) ? ps[t - off] : 0;
        __syncthreads();
        ps[t] = v + add;
        __syncthreads();
    }
    const int base = (t == 0) ? 0 : ps[t - 1];
    uint32* oc = ocnt + (size_t)blockIdx.x * NBUCK;
#pragma unroll
    for (int q = 0; q < 4; ++q) {
        int e0 = base + loc[q];
        lbase[t * 4 + q] = e0;
        oc[t * 4 + q] = (uint32)e0 | ((uint32)c[q] << 16);
    }
    __syncthreads();

#pragma unroll
    for (int k = 0; k < 8; ++k) st[lbase[bk[k]] + sl[k]] = pk[k];
    __syncthreads();
    uint32* gout = ebuf + (size_t)blockIdx.x * SPB;
#pragma unroll
    for (int k = 0; k < 8; ++k) gout[t + k * 256] = st[t + k * 256];
}

// ===== launch 2: mod-3 interleave — degb (roles 0,1) + 32-node support (role 2) =====
__global__ __launch_bounds__(256) void mid_kernel(
    const uint32* __restrict__ ebuf, const uint32* __restrict__ ocnt,
    float* __restrict__ dis, int* __restrict__ degarr,
    ushort* __restrict__ dadj, const float* __restrict__ x,
    const float* __restrict__ gamma, const float* __restrict__ beta,
    const ushort* __restrict__ Wp, const float* __restrict__ base_b,
    ushort* __restrict__ S) {
    __shared__ __align__(16) ushort smem[32 * KPAD2];       // 37,376 B
    const int t = threadIdx.x;
    const int lane = t & 63;
    const int w = t >> 6;
    const int role = blockIdx.x % 3;

    if (role < 2) {
        // ---- degb: bucket of 16 nodes; bitmask 16*MROW*4 = 33,024 B ----
        uint32* mask = (uint32*)smem;
        const int bkt = (blockIdx.x / 3) * 2 + role;
        for (int i = t; i < 16 * MROW; i += 256) mask[i] = 0;
        __syncthreads();

        const uint32 oc0 = ocnt[(size_t)t * NBUCK + bkt];
        const uint32 oc1 = ocnt[(size_t)(t + 256) * NBUCK + bkt];
#pragma unroll
        for (int h = 0; h < 2; ++h) {
            const int b = h ? (t + 256) : t;
            const uint32 oc = h ? oc1 : oc0;
            int off = (int)(oc & 0xFFFFu);
            int cn  = (int)(oc >> 16);
            const uint32* p = ebuf + (size_t)b * SPB + off;
            for (int s = 0; s < cn; ++s) {
                uint32 e = p[s];
                atomicOr(&mask[(e >> 14) * MROW + ((e & 16383) >> 5)],
                         1u << (e & 31));
            }
        }
        __syncthreads();

        for (int n = w * 4; n < w * 4 + 4; ++n) {
            const uint32* row = &mask[n * MROW];
            uint32 wd[8];
            int c = 0;
#pragma unroll
            for (int j = 0; j < 8; ++j) {
                wd[j] = row[lane + 64 * j];
                c += __popc(wd[j]);
            }
            int inc = c;
#pragma unroll
            for (int o = 1; o < 64; o <<= 1) {
                int v = __shfl_up(inc, o);
                if (lane >= o) inc += v;
            }
            int total = __shfl(inc, 63);
            int pos = inc - c;
            const int node = bkt * 16 + n;
            if (lane == 0) {
                dis[node] = rsqrtf((float)total);
                degarr[node] = total > DCAP ? DCAP : total;
            }
            ushort* drow = dadj + (size_t)node * DCAP;
#pragma unroll
            for (int j = 0; j < 8; ++j) {
                uint32 bits = wd[j];
                int base = (lane + 64 * j) * 32;
                while (bits) {
                    int b = __ffs(bits) - 1;
                    bits &= bits - 1;
                    if (pos < DCAP) drow[pos] = (ushort)(base + b);
                    ++pos;
                }
            }
        }
        return;
    }

    // ---- support: 32 nodes/block, two K-phases sharing Bs[32][KPAD2] ----
    ushort* Bs = smem;
    const int nodeBase = (blockIdx.x / 3) * 32;

    const float g0 = gamma[lane], g1 = gamma[lane + 64];
    const float be0 = beta[lane], be1 = beta[lane + 64];

    // prologue: LN for this wave's 8 nodes; keep h/f in registers
    float h0r[8], h1r[8], f0r[8], f1r[8];
#pragma unroll
    for (int j = 0; j < 8; ++j) {
        const int row = nodeBase + w * 8 + j;
        float f0 = x[(size_t)row * 128 + lane];
        float f1 = x[(size_t)row * 128 + lane + 64];
        float s = f0 + f1;
#pragma unroll
        for (int o = 32; o; o >>= 1) s += __shfl_xor(s, o);
        float mu = s * 0.0078125f;
        float d0 = f0 - mu, d1 = f1 - mu;
        float v = d0 * d0 + d1 * d1;
#pragma unroll
        for (int o = 32; o; o >>= 1) v += __shfl_xor(v, o);
        float rstd = rsqrtf(v * 0.0078125f + 1e-5f);
        h0r[j] = d0 * rstd * g0 + be0;
        h1r[j] = d1 * rstd * g1 + be1;
        f0r[j] = f0;
        f1r[j] = f1;
    }

    const int ct0 = w * 2;
    f32x4 accA = {0.f, 0.f, 0.f, 0.f};             // rows 0-15,  ct0
    f32x4 accB = {0.f, 0.f, 0.f, 0.f};             // rows 0-15,  ct0+1
    f32x4 accC = {0.f, 0.f, 0.f, 0.f};             // rows 16-31, ct0
    f32x4 accD = {0.f, 0.f, 0.f, 0.f};             // rows 16-31, ct0+1
    const ushort* Alo = &Bs[(lane & 15) * KPAD2 + (lane >> 4) * 8];
    const ushort* Ahi = Alo + 16 * KPAD2;
    const bf16x8* Wv = (const bf16x8*)Wp;

#pragma unroll
    for (int p = 0; p < 2; ++p) {
        if (p) __syncthreads();                    // protect phase-0 reads
        // write basis for phase p: channels p*64..p*64+63 (this wave's lane ch)
#pragma unroll
        for (int j = 0; j < 8; ++j) {
            const int n = w * 8 + j;
            const float h = p ? h1r[j] : h0r[j];
            const float f = p ? f1r[j] : f0r[j];
            ushort pk[8] __attribute__((aligned(16)));
#pragma unroll
            for (int g = 0; g < 8; ++g) {
                float gv = -2.0f + (float)g * (4.0f / 7.0f);
                float z = (h - gv) * 1.75f;
                pk[g] = f2bf(__expf(-z * z));
            }
            *reinterpret_cast<uint4*>(&Bs[n * KPAD2 + lane * 8]) =
                *reinterpret_cast<const uint4*>(pk);
            Bs[n * KPAD2 + 512 + lane] = f2bf(f / (1.0f + __expf(-f)));
        }
        __syncthreads();

        // GEMM phase p: kk global = p*18 + kkl
#pragma unroll 3
        for (int kkl = 0; kkl < KSTEPS_PH; ++kkl) {
            const int kkg = p * KSTEPS_PH + kkl;
            bf16x8 alo = *reinterpret_cast<const bf16x8*>(Alo + kkl * 32);
            bf16x8 ahi = *reinterpret_cast<const bf16x8*>(Ahi + kkl * 32);
            bf16x8 b0 = Wv[(size_t)(kkg * 8 + ct0) * 64 + lane];
            bf16x8 b1 = Wv[(size_t)(kkg * 8 + ct0 + 1) * 64 + lane];
            accA = __builtin_amdgcn_mfma_f32_16x16x32_bf16(alo, b0, accA, 0, 0, 0);
            accB = __builtin_amdgcn_mfma_f32_16x16x32_bf16(alo, b1, accB, 0, 0, 0);
            accC = __builtin_amdgcn_mfma_f32_16x16x32_bf16(ahi, b0, accC, 0, 0, 0);
            accD = __builtin_amdgcn_mfma_f32_16x16x32_bf16(ahi, b1, accD, 0, 0, 0);
        }
    }

    const int col0 = ct0 * 16 + (lane & 15);
    const int rbase = (lane >> 4) * 4;
    const float bb0 = base_b[col0];
    const float bb1 = base_b[col0 + 16];
#pragma unroll
    for (int r = 0; r < 4; ++r) {
        const int rlo = nodeBase + rbase + r;
        const int rhi = rlo + 16;
        S[(size_t)rlo * 128 + col0]      = f2bf(accA[r] + bb0);
        S[(size_t)rlo * 128 + col0 + 16] = f2bf(accB[r] + bb1);
        S[(size_t)rhi * 128 + col0]      = f2bf(accC[r] + bb0);
        S[(size_t)rhi * 128 + col0 + 16] = f2bf(accD[r] + bb1);
    }
}

// ===== launch 3: aggregation with uint4 row-gathers =====
// 2 nodes/block (g = t>>7); per node 2 waves; each wave-load covers 4 rows
// (16 lanes x 16B per row); 2 quads in flight per wave.
__global__ __launch_bounds__(256) void aggregate_kernel(
    const int* __restrict__ degarr, const ushort* __restrict__ dadj,
    const ushort* __restrict__ S, const float* __restrict__ dis,
    const float* __restrict__ bias, float* __restrict__ out) {
    __shared__ ushort lst[2][DCAP];
    __shared__ float part[2][2][128];
    const int t = threadIdx.x;
    const int g = t >> 7;
    const int tl = t & 127;
    const int i = blockIdx.x * 2 + g;

    const int total = degarr[i];
    const ushort* drow = dadj + (size_t)i * DCAP;
    if (tl < total) lst[g][tl] = drow[tl];
    if (tl + 128 < total) lst[g][tl + 128] = drow[tl + 128];
    __syncthreads();

    const int lane = t & 63;
    const int wv = (t >> 6) & 1;
    const int slot = lane >> 4;                      // row slot 0..3 in quad
    const int cl = lane & 15;                        // 16B chunk within row
    const uint4* S128 = (const uint4*)S;             // row stride 16 uint4
    float acc[8] = {0.f, 0.f, 0.f, 0.f, 0.f, 0.f, 0.f, 0.f};

    // wave wv handles quads at base = wv*4 + 16*k (A) and +8 (B)
    for (int base = wv * 4; base < total; base += 16) {
        const int ia = base + slot;
        const int ib = base + 8 + slot;
        const int ja = lst[g][ia < total ? ia : (total - 1)];
        const int jb = lst[g][ib < total ? ib : (total - 1)];
        const float da = (ia < total) ? dis[ja] : 0.0f;
        const float db = (ib < total) ? dis[jb] : 0.0f;
        const uint4 ua = S128[(size_t)ja * 16 + cl];
        const uint4 ub = S128[(size_t)jb * 16 + cl];
        acc[0] += da * bflo(ua.x) + db * bflo(ub.x);
        acc[1] += da * bfhi(ua.x) + db * bfhi(ub.x);
        acc[2] += da * bflo(ua.y) + db * bflo(ub.y);
        acc[3] += da * bfhi(ua.y) + db * bfhi(ub.y);
        acc[4] += da * bflo(ua.z) + db * bflo(ub.z);
        acc[5] += da * bfhi(ua.z) + db * bfhi(ub.z);
        acc[6] += da * bflo(ua.w) + db * bflo(ub.w);
        acc[7] += da * bfhi(ua.w) + db * bfhi(ub.w);
    }

    // reduce across the 4 row-slots (lanes differing in bits 4,5)
#pragma unroll
    for (int e = 0; e < 8; ++e) {
        acc[e] += __shfl_xor(acc[e], 16);
        acc[e] += __shfl_xor(acc[e], 32);
    }
    if (lane < 16) {
        float4 v0 = {acc[0], acc[1], acc[2], acc[3]};
        float4 v1 = {acc[4], acc[5], acc[6], acc[7]};
        *reinterpret_cast<float4*>(&part[g][wv][cl * 8])     = v0;
        *reinterpret_cast<float4*>(&part[g][wv][cl * 8 + 4]) = v1;
    }
    __syncthreads();

    float v = part[g][0][tl] + part[g][1][tl];
    out[(size_t)i * 128 + tl] = v * dis[i] + bias[tl];
}

extern "C" void kernel_launch(void* const* d_in, const int* in_sizes, int n_in,
                              void* d_out, int out_size, void* d_ws, size_t ws_size,
                              hipStream_t stream) {
    const float* x        = (const float*)d_in[0];
    const int*   ei       = (const int*)d_in[1];
    const float* ln_gamma = (const float*)d_in[2];
    const float* ln_beta  = (const float*)d_in[3];
    const float* spline_w = (const float*)d_in[4];
    const float* base_w   = (const float*)d_in[5];
    const float* base_b   = (const float*)d_in[6];
    const float* bias     = (const float*)d_in[7];
    float* out = (float*)d_out;

    char* ws = (char*)d_ws;
    const size_t WP_OFF   = 0;             //    294,912 B
    const size_t DIS_OFF  = 294912;        //     65,536 B
    const size_t DEG_OFF  = 360448;        //     65,536 B
    const size_t DADJ_OFF = 425984;        //  8,388,608 B
    const size_t OCNT_OFF = 8814592;       //  2,097,152 B (512 x 1024 u32)
    const size_t EBUF_OFF = 10911744;      //  4,194,304 B
    const size_t S_OFF    = 15106048;      //  4,194,304 B
    const size_t NEEDED   = 19300352;
    if (ws_size < NEEDED) return;

    ushort* Wp     = (ushort*)(ws + WP_OFF);
    float*  dis    = (float*)(ws + DIS_OFF);
    int*    degarr = (int*)(ws + DEG_OFF);
    ushort* dadj   = (ushort*)(ws + DADJ_OFF);
    uint32* ocnt   = (uint32*)(ws + OCNT_OFF);
    uint32* ebuf   = (uint32*)(ws + EBUF_OFF);
    ushort* S      = (ushort*)(ws + S_OFF);

    pre_kernel<<<SBLK + 576, 256, 0, stream>>>(ei, ebuf, ocnt,
                                               spline_w, base_w, Wp);
    mid_kernel<<<1536, 256, 0, stream>>>(ebuf, ocnt, dis, degarr, dadj,
                                         x, ln_gamma, ln_beta, Wp, base_b, S);
    aggregate_kernel<<<N_NODES / 2, 256, 0, stream>>>(degarr, dadj, S, dis,
                                                      bias, out);
}